// Round 17
// baseline (88.875 us; speedup 1.0000x reference)
//
#include <hip/hip_runtime.h>
#include <stdint.h>

typedef __attribute__((ext_vector_type(8))) __bf16 bf16x8;
typedef __attribute__((ext_vector_type(4))) float f32x4;

__device__ __forceinline__ unsigned short f2bf(float f) {
  union { float f; unsigned int u; } v; v.f = f;
  unsigned int u = v.u;
  return (unsigned short)((u + 0x7fffu + ((u >> 16) & 1u)) >> 16);
}

__device__ __forceinline__ void async_copy16(const void* g, void* s) {
  __builtin_amdgcn_global_load_lds(
      (__attribute__((address_space(1))) void*)const_cast<void*>(g),
      (__attribute__((address_space(3))) void*)s,
      16, 0, 0);
}

#define HAAR(a, bb, cc, dd, oA, oH, oV, oD)                                    \
  oA = 0.5f * ((a + bb) + (cc + dd));                                          \
  oH = 0.5f * ((a + bb) - (cc + dd));                                          \
  oV = 0.5f * ((a - bb) + (cc - dd));                                          \
  oD = 0.5f * ((a - bb) - (cc - dd));

// ---- fused pre-kernel: blocks [0,576) = W fp32->bf16; [576,5280) = DWT ---
__global__ __launch_bounds__(256) void pre_kernel(const float* __restrict__ x,
                                                  const float* __restrict__ W,
                                                  unsigned short* __restrict__ A,
                                                  unsigned short* __restrict__ Wb) {
  if (blockIdx.x < 576) {
    int i = blockIdx.x * 256 + threadIdx.x;  // 147456 threads x 4 floats
    float4 v = ((const float4*)W)[i];
    uint2 o;
    o.x = (unsigned int)f2bf(v.x) | ((unsigned int)f2bf(v.y) << 16);
    o.y = (unsigned int)f2bf(v.z) | ((unsigned int)f2bf(v.w) << 16);
    ((uint2*)Wb)[i] = o;
    return;
  }

  int tid = (blockIdx.x - 576) * 256 + threadIdx.x;  // 128*3*56*56 = 1204224
  int J = tid % 56;
  int t = tid / 56;
  int I = t % 56;
  t /= 56;  // t = b*3 + c
  int c = t % 3;
  int b = t / 3;

  const float* xp = x + (((size_t)t * 224 + 4 * I) * 224 + 4 * J);
  float4 r0 = *(const float4*)(xp);
  float4 r1 = *(const float4*)(xp + 224);
  float4 r2 = *(const float4*)(xp + 448);
  float4 r3 = *(const float4*)(xp + 672);

  float A1[2][2], H1[2][2], V1[2][2], D1[2][2];
  HAAR(r0.x, r0.y, r1.x, r1.y, A1[0][0], H1[0][0], V1[0][0], D1[0][0]);
  HAAR(r0.z, r0.w, r1.z, r1.w, A1[0][1], H1[0][1], V1[0][1], D1[0][1]);
  HAAR(r2.x, r2.y, r3.x, r3.y, A1[1][0], H1[1][0], V1[1][0], D1[1][0]);
  HAAR(r2.z, r2.w, r3.z, r3.w, A1[1][1], H1[1][1], V1[1][1], D1[1][1]);

  auto aidx = [&](int y, int xx) -> size_t {
    int mrow = b * 196 + (y >> 4) * 14 + (xx >> 4);
    int k = c * 256 + (y & 15) * 16 + (xx & 15);
    return (size_t)mrow * 768 + (size_t)k;
  };
  auto store2 = [&](int y, int xx, float v0, float v1) {
    unsigned int p = (unsigned int)f2bf(v0) | ((unsigned int)f2bf(v1) << 16);
    *(unsigned int*)(A + aidx(y, xx)) = p;  // xx even -> 4B aligned, same patch
  };

  int y0 = 2 * I, x0 = 2 * J;
  store2(y0,           112 + x0, H1[0][0], H1[0][1]);
  store2(y0 + 1,       112 + x0, H1[1][0], H1[1][1]);
  store2(112 + y0,     x0,       V1[0][0], V1[0][1]);
  store2(112 + y0 + 1, x0,       V1[1][0], V1[1][1]);
  store2(112 + y0,     112 + x0, D1[0][0], D1[0][1]);
  store2(112 + y0 + 1, 112 + x0, D1[1][0], D1[1][1]);

  float vA2, vH2, vV2, vD2;
  HAAR(A1[0][0], A1[0][1], A1[1][0], A1[1][1], vA2, vH2, vV2, vD2);
  A[aidx(I,      J)]      = f2bf(vA2);
  A[aidx(I,      56 + J)] = f2bf(vH2);
  A[aidx(56 + I, J)]      = f2bf(vV2);
  A[aidx(56 + I, 56 + J)] = f2bf(vD2);
}

// --------- bf16 MFMA GEMM: C[M][N] = A[M][K] * Bt[N][K]^T + bias -----------
// M=25088, N=768, K=768. 128x128 block, BK=64, DOUBLE-buffer = 64 KB LDS
// (guaranteed 2 blocks/CU even with runtime LDS reserve — r13's 80 KB ran
// 1 block/CU per the occupancy counter). 4 waves of 64x64, grid 1176.
// r16 schedule: stage-at-top, compiler-scheduled lgkm inside, iter-end
// {lgkmcnt(0), vmcnt(0), barrier}. XOR swizzle P(row)=row&7.
__global__ __launch_bounds__(256) void gemm_kernel(const unsigned short* __restrict__ A,
                                                   const unsigned short* __restrict__ Bt,
                                                   const float* __restrict__ bias,
                                                   float* __restrict__ C) {
  constexpr int K = 768, N = 768;
  constexpr int NT = 12;  // K / 64
  __shared__ unsigned short As[2][128 * 64];  // 16 KB per buffer
  __shared__ unsigned short Bs[2][128 * 64];  // 16 KB per buffer

  // XCD swizzle: 1176 = 8 XCDs x 147 consecutive tiles (bijective).
  const int orig = blockIdx.x;
  const int tile = (orig & 7) * 147 + (orig >> 3);
  const int bm = tile / 6, bn = tile % 6;
  const int mbase = bm * 128, nbase = bn * 128;

  const int tid = threadIdx.x;
  const int lane = tid & 63;
  const int wave = tid >> 6;
  const int wr = wave >> 1, wc = wave & 1;  // wave tile 64x64

  f32x4 acc[4][4] = {};

  // staging: per operand per buffer 16 KB; wave covers 4 KB = 4 insts.
  // dest row (inst i) = i*32 + wave*8 + (lane>>3), phys chunk = lane&7.
  // source chunk pre-swizzled: kcs = (lane&7) ^ ((lane>>3)&7)  (row&7 =
  // (lane>>3)&7; i/wave terms vanish mod 8 — involution matches read chq).
  const int srow = wave * 8 + (lane >> 3);
  const int kcs = (lane & 7) ^ ((lane >> 3) & 7);
  const unsigned short* gA[4];
  const unsigned short* gB[4];
#pragma unroll
  for (int i = 0; i < 4; ++i) {
    gA[i] = A + (size_t)(mbase + i * 32 + srow) * K + kcs * 8;
    gB[i] = Bt + (size_t)(nbase + i * 32 + srow) * K + kcs * 8;
  }

  auto stage = [&](int buf, int kt) {
    char* sa = (char*)As + buf * 16384 + wave * 1024;
    char* sb = (char*)Bs + buf * 16384 + wave * 1024;
    const int ko = kt * 64;
#pragma unroll
    for (int i = 0; i < 4; ++i) {
      async_copy16(gA[i] + ko, sa + i * 4096);
      async_copy16(gB[i] + ko, sb + i * 4096);
    }
  };

  // fragment read geometry: row stride 128B; chunk (s*4+kq) ^ (fr&7)
  const int fr = lane & 15;
  const int kq = lane >> 4;
  const int ch0 = ((0 * 4 + kq) ^ (fr & 7)) * 16;
  const int ch1 = ((1 * 4 + kq) ^ (fr & 7)) * 16;

  stage(0, 0);
  asm volatile("s_waitcnt vmcnt(0)" ::: "memory");
  __builtin_amdgcn_s_barrier();

#pragma unroll
  for (int kt = 0; kt < NT; ++kt) {
    const int cb = kt & 1;
    // stage next tile first: full-iter lead. Race-free: writes buf[cb^1],
    // whose readers were lgkm-fenced before the barrier we just crossed.
    if (kt + 1 < NT) stage(cb ^ 1, kt + 1);

    const char* pa = (const char*)As + cb * 16384 + (wr * 64 + fr) * 128;
    const char* pb = (const char*)Bs + cb * 16384 + (wc * 64 + fr) * 128;
    bf16x8 af[4], bv[4];

    // k-half 0 (compiler inserts incremental lgkmcnt before each MFMA)
#pragma unroll
    for (int ni = 0; ni < 4; ++ni) bv[ni] = *(const bf16x8*)(pb + ni * 2048 + ch0);
#pragma unroll
    for (int mi = 0; mi < 4; ++mi) af[mi] = *(const bf16x8*)(pa + mi * 2048 + ch0);
#pragma unroll
    for (int mi = 0; mi < 4; ++mi)
#pragma unroll
      for (int ni = 0; ni < 4; ++ni)
        acc[mi][ni] = __builtin_amdgcn_mfma_f32_16x16x32_bf16(af[mi], bv[ni],
                                                              acc[mi][ni], 0, 0, 0);
    // k-half 1
#pragma unroll
    for (int ni = 0; ni < 4; ++ni) bv[ni] = *(const bf16x8*)(pb + ni * 2048 + ch1);
#pragma unroll
    for (int mi = 0; mi < 4; ++mi) af[mi] = *(const bf16x8*)(pa + mi * 2048 + ch1);
#pragma unroll
    for (int mi = 0; mi < 4; ++mi)
#pragma unroll
      for (int ni = 0; ni < 4; ++ni)
        acc[mi][ni] = __builtin_amdgcn_mfma_f32_16x16x32_bf16(af[mi], bv[ni],
                                                              acc[mi][ni], 0, 0, 0);

    if (kt + 1 < NT) {
      asm volatile("s_waitcnt lgkmcnt(0)" ::: "memory");  // my reads of buf[cb] done
      asm volatile("s_waitcnt vmcnt(0)" ::: "memory");    // my stages landed
      __builtin_amdgcn_s_barrier();                       // all waves ready
    }
  }

  // epilogue: C col = lane&15, row = (lane>>4)*4 + j ; fuse bias
  const int rq = lane >> 4;
#pragma unroll
  for (int ni = 0; ni < 4; ++ni) {
    int n = nbase + wc * 64 + ni * 16 + fr;
    float bb = bias[n];
#pragma unroll
    for (int mi = 0; mi < 4; ++mi) {
      int mrow = mbase + wr * 64 + mi * 16 + rq * 4;
      f32x4 v = acc[mi][ni];
#pragma unroll
      for (int j = 0; j < 4; ++j) C[(size_t)(mrow + j) * N + n] = v[j] + bb;
    }
  }
}

extern "C" void kernel_launch(void* const* d_in, const int* in_sizes, int n_in,
                              void* d_out, int out_size, void* d_ws, size_t ws_size,
                              hipStream_t stream) {
  const float* x = (const float*)d_in[0];     // (128,3,224,224) f32
  const float* W = (const float*)d_in[1];     // (768,3,16,16)  f32
  const float* bias = (const float*)d_in[2];  // (768,)         f32
  float* out = (float*)d_out;                 // (128,196,768)  f32

  unsigned short* A = (unsigned short*)d_ws;                        // 25088*768 bf16
  unsigned short* Wb = (unsigned short*)((char*)d_ws + 38535168);   // 589824 bf16

  pre_kernel<<<5280, 256, 0, stream>>>(x, W, A, Wb);
  gemm_kernel<<<1176, 256, 0, stream>>>(A, Wb, bias, out);
}

// Round 18
// 72.639 us; speedup vs baseline: 1.2235x; 1.2235x over previous
//
#include <hip/hip_runtime.h>
#include <stdint.h>

typedef __attribute__((ext_vector_type(8))) __bf16 bf16x8;
typedef __attribute__((ext_vector_type(4))) float f32x4;

__device__ __forceinline__ unsigned short f2bf(float f) {
  union { float f; unsigned int u; } v; v.f = f;
  unsigned int u = v.u;
  return (unsigned short)((u + 0x7fffu + ((u >> 16) & 1u)) >> 16);
}

__device__ __forceinline__ void async_copy16(const void* g, void* s) {
  __builtin_amdgcn_global_load_lds(
      (__attribute__((address_space(1))) void*)const_cast<void*>(g),
      (__attribute__((address_space(3))) void*)s,
      16, 0, 0);
}

#define HAAR(a, bb, cc, dd, oA, oH, oV, oD)                                    \
  oA = 0.5f * ((a + bb) + (cc + dd));                                          \
  oH = 0.5f * ((a + bb) - (cc + dd));                                          \
  oV = 0.5f * ((a - bb) + (cc - dd));                                          \
  oD = 0.5f * ((a - bb) - (cc - dd));

// ---- fused pre-kernel: blocks [0,576) = W fp32->bf16; [576,5280) = DWT ---
__global__ __launch_bounds__(256) void pre_kernel(const float* __restrict__ x,
                                                  const float* __restrict__ W,
                                                  unsigned short* __restrict__ A,
                                                  unsigned short* __restrict__ Wb) {
  if (blockIdx.x < 576) {
    int i = blockIdx.x * 256 + threadIdx.x;  // 147456 threads x 4 floats
    float4 v = ((const float4*)W)[i];
    uint2 o;
    o.x = (unsigned int)f2bf(v.x) | ((unsigned int)f2bf(v.y) << 16);
    o.y = (unsigned int)f2bf(v.z) | ((unsigned int)f2bf(v.w) << 16);
    ((uint2*)Wb)[i] = o;
    return;
  }

  int tid = (blockIdx.x - 576) * 256 + threadIdx.x;  // 128*3*56*56 = 1204224
  int J = tid % 56;
  int t = tid / 56;
  int I = t % 56;
  t /= 56;  // t = b*3 + c
  int c = t % 3;
  int b = t / 3;

  const float* xp = x + (((size_t)t * 224 + 4 * I) * 224 + 4 * J);
  float4 r0 = *(const float4*)(xp);
  float4 r1 = *(const float4*)(xp + 224);
  float4 r2 = *(const float4*)(xp + 448);
  float4 r3 = *(const float4*)(xp + 672);

  float A1[2][2], H1[2][2], V1[2][2], D1[2][2];
  HAAR(r0.x, r0.y, r1.x, r1.y, A1[0][0], H1[0][0], V1[0][0], D1[0][0]);
  HAAR(r0.z, r0.w, r1.z, r1.w, A1[0][1], H1[0][1], V1[0][1], D1[0][1]);
  HAAR(r2.x, r2.y, r3.x, r3.y, A1[1][0], H1[1][0], V1[1][0], D1[1][0]);
  HAAR(r2.z, r2.w, r3.z, r3.w, A1[1][1], H1[1][1], V1[1][1], D1[1][1]);

  auto aidx = [&](int y, int xx) -> size_t {
    int mrow = b * 196 + (y >> 4) * 14 + (xx >> 4);
    int k = c * 256 + (y & 15) * 16 + (xx & 15);
    return (size_t)mrow * 768 + (size_t)k;
  };
  auto store2 = [&](int y, int xx, float v0, float v1) {
    unsigned int p = (unsigned int)f2bf(v0) | ((unsigned int)f2bf(v1) << 16);
    *(unsigned int*)(A + aidx(y, xx)) = p;  // xx even -> 4B aligned, same patch
  };

  int y0 = 2 * I, x0 = 2 * J;
  store2(y0,           112 + x0, H1[0][0], H1[0][1]);
  store2(y0 + 1,       112 + x0, H1[1][0], H1[1][1]);
  store2(112 + y0,     x0,       V1[0][0], V1[0][1]);
  store2(112 + y0 + 1, x0,       V1[1][0], V1[1][1]);
  store2(112 + y0,     112 + x0, D1[0][0], D1[0][1]);
  store2(112 + y0 + 1, 112 + x0, D1[1][0], D1[1][1]);

  float vA2, vH2, vV2, vD2;
  HAAR(A1[0][0], A1[0][1], A1[1][0], A1[1][1], vA2, vH2, vV2, vD2);
  A[aidx(I,      J)]      = f2bf(vA2);
  A[aidx(I,      56 + J)] = f2bf(vH2);
  A[aidx(56 + I, J)]      = f2bf(vV2);
  A[aidx(56 + I, 56 + J)] = f2bf(vD2);
}

// --------- bf16 MFMA GEMM: C[M][N] = A[M][K] * Bt[N][K]^T + bias -----------
// M=25088, N=768, K=768. 256x256 block, BK=64, dbuf (128 KB LDS), 512 thr
// = 8 waves of 128x64 (acc[8][4]). MECHANISM: per-CU block-iteration count
// drops 36.7 (r16) -> ~24 (294 blocks ~= 2 rounds x 12 iters); each serial
// latency chain (vmcnt drain + barrier + read->MFMA) amortizes 4x the MFMA
// work. Schedule = r16 exact: stage-at-top, compiler lgkm inside, iter-end
// {lgkmcnt(0), vmcnt(0), barrier}. Proven swizzle P(row)=row&7 (0 conflicts).
__global__ __launch_bounds__(512, 1) void gemm_kernel(const unsigned short* __restrict__ A,
                                                      const unsigned short* __restrict__ Bt,
                                                      const float* __restrict__ bias,
                                                      float* __restrict__ C) {
  constexpr int K = 768, N = 768;
  constexpr int NT = 12;  // K / 64
  __shared__ unsigned short As[2][256 * 64];  // 32 KB per buffer
  __shared__ unsigned short Bs[2][256 * 64];  // 32 KB per buffer

  // bijective m204 XCD swizzle: 294 = 8*36 + 6 (q=36, r=6)
  const int orig = blockIdx.x;
  const int xcd = orig & 7, idx = orig >> 3;
  const int wgid = (xcd < 6 ? xcd * 37 : 222 + (xcd - 6) * 36) + idx;
  const int bm = wgid / 3, bn = wgid % 3;  // bn fastest: neighbors share A
  const int mbase = bm * 256, nbase = bn * 256;

  const int tid = threadIdx.x;
  const int lane = tid & 63;
  const int wave = tid >> 6;   // 0..7
  const int wm = wave >> 2;    // 0..1 -> rows [wm*128, +128)
  const int wn = wave & 3;     // 0..3 -> cols [wn*64, +64)

  f32x4 acc[8][4] = {};  // wave output 128x64

  // staging: per operand per buffer 32 KB; wave covers 4 KB/inst-round,
  // 4 insts each. dest row (inst i) = i*64 + wave*8 + (lane>>3), phys
  // chunk = lane&7; source chunk pre-swizzled kcs = (lane&7)^((lane>>3)&7)
  // (row&7 = (lane>>3)&7; i/wave terms vanish mod 8 — proven involution).
  const int srow = wave * 8 + (lane >> 3);
  const int kcs = (lane & 7) ^ ((lane >> 3) & 7);
  const unsigned short* gA[4];
  const unsigned short* gB[4];
#pragma unroll
  for (int i = 0; i < 4; ++i) {
    gA[i] = A + (size_t)(mbase + i * 64 + srow) * K + kcs * 8;
    gB[i] = Bt + (size_t)(nbase + i * 64 + srow) * K + kcs * 8;
  }

  auto stage = [&](int buf, int kt) {
    char* sa = (char*)As + buf * 32768 + wave * 1024;
    char* sb = (char*)Bs + buf * 32768 + wave * 1024;
    const int ko = kt * 64;
#pragma unroll
    for (int i = 0; i < 4; ++i) {
      async_copy16(gA[i] + ko, sa + i * 8192);
      async_copy16(gB[i] + ko, sb + i * 8192);
    }
  };

  // fragment read geometry: row stride 128B; chunk (s*4+kq) ^ (fr&7)
  const int fr = lane & 15;
  const int kq = lane >> 4;
  const int ch0 = ((0 * 4 + kq) ^ (fr & 7)) * 16;
  const int ch1 = ((1 * 4 + kq) ^ (fr & 7)) * 16;

  stage(0, 0);
  asm volatile("s_waitcnt vmcnt(0)" ::: "memory");
  __builtin_amdgcn_s_barrier();

#pragma unroll
  for (int kt = 0; kt < NT; ++kt) {
    const int cb = kt & 1;
    // stage next tile first: full-iter lead. Race-free: writes buf[cb^1],
    // whose readers were lgkm-fenced before the barrier we just crossed.
    if (kt + 1 < NT) stage(cb ^ 1, kt + 1);

    const char* pa = (const char*)As + cb * 32768 + (wm * 128 + fr) * 128;
    const char* pb = (const char*)Bs + cb * 32768 + (wn * 64 + fr) * 128;
    bf16x8 af[8], bv[4];

    // k-half 0 (compiler inserts incremental lgkmcnt before each MFMA)
#pragma unroll
    for (int ni = 0; ni < 4; ++ni) bv[ni] = *(const bf16x8*)(pb + ni * 2048 + ch0);
#pragma unroll
    for (int mi = 0; mi < 8; ++mi) af[mi] = *(const bf16x8*)(pa + mi * 2048 + ch0);
#pragma unroll
    for (int mi = 0; mi < 8; ++mi)
#pragma unroll
      for (int ni = 0; ni < 4; ++ni)
        acc[mi][ni] = __builtin_amdgcn_mfma_f32_16x16x32_bf16(af[mi], bv[ni],
                                                              acc[mi][ni], 0, 0, 0);
    // k-half 1
#pragma unroll
    for (int ni = 0; ni < 4; ++ni) bv[ni] = *(const bf16x8*)(pb + ni * 2048 + ch1);
#pragma unroll
    for (int mi = 0; mi < 8; ++mi) af[mi] = *(const bf16x8*)(pa + mi * 2048 + ch1);
#pragma unroll
    for (int mi = 0; mi < 8; ++mi)
#pragma unroll
      for (int ni = 0; ni < 4; ++ni)
        acc[mi][ni] = __builtin_amdgcn_mfma_f32_16x16x32_bf16(af[mi], bv[ni],
                                                              acc[mi][ni], 0, 0, 0);

    if (kt + 1 < NT) {
      asm volatile("s_waitcnt lgkmcnt(0)" ::: "memory");  // my reads of buf[cb] done
      asm volatile("s_waitcnt vmcnt(0)" ::: "memory");    // my stages landed
      __builtin_amdgcn_s_barrier();                       // all waves ready
    }
  }

  // epilogue: C col = lane&15, row = (lane>>4)*4 + j ; fuse bias
  const int rq = lane >> 4;
#pragma unroll
  for (int ni = 0; ni < 4; ++ni) {
    int n = nbase + wn * 64 + ni * 16 + fr;
    float bb = bias[n];
#pragma unroll
    for (int mi = 0; mi < 8; ++mi) {
      int mrow = mbase + wm * 128 + mi * 16 + rq * 4;
      f32x4 v = acc[mi][ni];
#pragma unroll
      for (int j = 0; j < 4; ++j) C[(size_t)(mrow + j) * N + n] = v[j] + bb;
    }
  }
}

extern "C" void kernel_launch(void* const* d_in, const int* in_sizes, int n_in,
                              void* d_out, int out_size, void* d_ws, size_t ws_size,
                              hipStream_t stream) {
  const float* x = (const float*)d_in[0];     // (128,3,224,224) f32
  const float* W = (const float*)d_in[1];     // (768,3,16,16)  f32
  const float* bias = (const float*)d_in[2];  // (768,)         f32
  float* out = (float*)d_out;                 // (128,196,768)  f32

  unsigned short* A = (unsigned short*)d_ws;                        // 25088*768 bf16
  unsigned short* Wb = (unsigned short*)((char*)d_ws + 38535168);   // 589824 bf16

  pre_kernel<<<5280, 256, 0, stream>>>(x, W, A, Wb);
  gemm_kernel<<<294, 512, 0, stream>>>(A, Wb, bias, out);
}

// Round 19
// 62.918 us; speedup vs baseline: 1.4126x; 1.1545x over previous
//
#include <hip/hip_runtime.h>
#include <stdint.h>

typedef __attribute__((ext_vector_type(8))) __bf16 bf16x8;
typedef __attribute__((ext_vector_type(4))) float f32x4;

__device__ __forceinline__ unsigned short f2bf(float f) {
  union { float f; unsigned int u; } v; v.f = f;
  unsigned int u = v.u;
  return (unsigned short)((u + 0x7fffu + ((u >> 16) & 1u)) >> 16);
}

__device__ __forceinline__ void async_copy16(const void* g, void* s) {
  __builtin_amdgcn_global_load_lds(
      (__attribute__((address_space(1))) void*)const_cast<void*>(g),
      (__attribute__((address_space(3))) void*)s,
      16, 0, 0);
}

#define HAAR(a, bb, cc, dd, oA, oH, oV, oD)                                    \
  oA = 0.5f * ((a + bb) + (cc + dd));                                          \
  oH = 0.5f * ((a + bb) - (cc + dd));                                          \
  oV = 0.5f * ((a - bb) + (cc - dd));                                          \
  oD = 0.5f * ((a - bb) - (cc - dd));

// ---- fused pre-kernel: blocks [0,576) = W fp32->bf16; [576,5280) = DWT ---
__global__ __launch_bounds__(256) void pre_kernel(const float* __restrict__ x,
                                                  const float* __restrict__ W,
                                                  unsigned short* __restrict__ A,
                                                  unsigned short* __restrict__ Wb) {
  if (blockIdx.x < 576) {
    int i = blockIdx.x * 256 + threadIdx.x;  // 147456 threads x 4 floats
    float4 v = ((const float4*)W)[i];
    uint2 o;
    o.x = (unsigned int)f2bf(v.x) | ((unsigned int)f2bf(v.y) << 16);
    o.y = (unsigned int)f2bf(v.z) | ((unsigned int)f2bf(v.w) << 16);
    ((uint2*)Wb)[i] = o;
    return;
  }

  int tid = (blockIdx.x - 576) * 256 + threadIdx.x;  // 128*3*56*56 = 1204224
  int J = tid % 56;
  int t = tid / 56;
  int I = t % 56;
  t /= 56;  // t = b*3 + c
  int c = t % 3;
  int b = t / 3;

  const float* xp = x + (((size_t)t * 224 + 4 * I) * 224 + 4 * J);
  float4 r0 = *(const float4*)(xp);
  float4 r1 = *(const float4*)(xp + 224);
  float4 r2 = *(const float4*)(xp + 448);
  float4 r3 = *(const float4*)(xp + 672);

  float A1[2][2], H1[2][2], V1[2][2], D1[2][2];
  HAAR(r0.x, r0.y, r1.x, r1.y, A1[0][0], H1[0][0], V1[0][0], D1[0][0]);
  HAAR(r0.z, r0.w, r1.z, r1.w, A1[0][1], H1[0][1], V1[0][1], D1[0][1]);
  HAAR(r2.x, r2.y, r3.x, r3.y, A1[1][0], H1[1][0], V1[1][0], D1[1][0]);
  HAAR(r2.z, r2.w, r3.z, r3.w, A1[1][1], H1[1][1], V1[1][1], D1[1][1]);

  auto aidx = [&](int y, int xx) -> size_t {
    int mrow = b * 196 + (y >> 4) * 14 + (xx >> 4);
    int k = c * 256 + (y & 15) * 16 + (xx & 15);
    return (size_t)mrow * 768 + (size_t)k;
  };
  auto store2 = [&](int y, int xx, float v0, float v1) {
    unsigned int p = (unsigned int)f2bf(v0) | ((unsigned int)f2bf(v1) << 16);
    *(unsigned int*)(A + aidx(y, xx)) = p;  // xx even -> 4B aligned, same patch
  };

  int y0 = 2 * I, x0 = 2 * J;
  store2(y0,           112 + x0, H1[0][0], H1[0][1]);
  store2(y0 + 1,       112 + x0, H1[1][0], H1[1][1]);
  store2(112 + y0,     x0,       V1[0][0], V1[0][1]);
  store2(112 + y0 + 1, x0,       V1[1][0], V1[1][1]);
  store2(112 + y0,     112 + x0, D1[0][0], D1[0][1]);
  store2(112 + y0 + 1, 112 + x0, D1[1][0], D1[1][1]);

  float vA2, vH2, vV2, vD2;
  HAAR(A1[0][0], A1[0][1], A1[1][0], A1[1][1], vA2, vH2, vV2, vD2);
  A[aidx(I,      J)]      = f2bf(vA2);
  A[aidx(I,      56 + J)] = f2bf(vH2);
  A[aidx(56 + I, J)]      = f2bf(vV2);
  A[aidx(56 + I, 56 + J)] = f2bf(vD2);
}

// --------- bf16 MFMA GEMM (r16 = session best): 128x192, BK=64, dbuf ------
// M=25088, N=768, K=768. 4 waves of 64x96. Stage-at-top (full-iter load
// lead), compiler-scheduled lgkm inside, iter-end {lgkmcnt(0), vmcnt(0),
// barrier}. XOR swizzle P(row)=row&7 (0 conflicts). 784 = 8 XCDs x 98.
// Measured: 45.3-45.7 us, MfmaUtil ~25%, no pipe saturated — the 2-phase
// structural ceiling at this shape (18 structures bracket it).
__global__ __launch_bounds__(256) void gemm_kernel(const unsigned short* __restrict__ A,
                                                   const unsigned short* __restrict__ Bt,
                                                   const float* __restrict__ bias,
                                                   float* __restrict__ C) {
  constexpr int K = 768, N = 768;
  constexpr int NT = 12;  // K / 64
  __shared__ unsigned short As[2][128 * 64];  // 16 KB per buffer
  __shared__ unsigned short Bs[2][192 * 64];  // 24 KB per buffer

  const int orig = blockIdx.x;
  const int tile = (orig & 7) * 98 + (orig >> 3);
  const int bm = tile >> 2, bn = tile & 3;
  const int mbase = bm * 128, nbase = bn * 192;

  const int tid = threadIdx.x;
  const int lane = tid & 63;
  const int wave = tid >> 6;
  const int wr = wave >> 1, wc = wave & 1;  // wave tile 64x96

  f32x4 acc[4][6] = {};

  const int srow = wave * 8 + (lane >> 3);
  const int kcs = (lane & 7) ^ ((lane >> 3) & 7);
  const unsigned short* gA[4];
  const unsigned short* gB[6];
#pragma unroll
  for (int i = 0; i < 4; ++i) gA[i] = A + (size_t)(mbase + i * 32 + srow) * K + kcs * 8;
#pragma unroll
  for (int j = 0; j < 6; ++j) gB[j] = Bt + (size_t)(nbase + j * 32 + srow) * K + kcs * 8;

  auto stage = [&](int buf, int kt) {
    char* sa = (char*)As + buf * 16384 + wave * 1024;
    char* sb = (char*)Bs + buf * 24576 + wave * 1024;
    const int ko = kt * 64;
#pragma unroll
    for (int i = 0; i < 4; ++i) async_copy16(gA[i] + ko, sa + i * 4096);
#pragma unroll
    for (int j = 0; j < 6; ++j) async_copy16(gB[j] + ko, sb + j * 4096);
  };

  const int fr = lane & 15;
  const int kq = lane >> 4;
  const int ch0 = ((0 * 4 + kq) ^ (fr & 7)) * 16;
  const int ch1 = ((1 * 4 + kq) ^ (fr & 7)) * 16;

  stage(0, 0);
  asm volatile("s_waitcnt vmcnt(0)" ::: "memory");
  __builtin_amdgcn_s_barrier();

#pragma unroll
  for (int kt = 0; kt < NT; ++kt) {
    const int cb = kt & 1;
    // stage next tile FIRST: loads get the whole iteration to land.
    // Race-free: writes buf[cb^1], whose readers (iter kt-1) were
    // lgkm-fenced before the barrier we just crossed.
    if (kt + 1 < NT) stage(cb ^ 1, kt + 1);

    const char* pa = (const char*)As + cb * 16384 + (wr * 64 + fr) * 128;
    const char* pb = (const char*)Bs + cb * 24576 + (wc * 96 + fr) * 128;
    bf16x8 af[4], bv[6];

    // k-half 0 (compiler inserts incremental lgkmcnt before each MFMA)
#pragma unroll
    for (int ni = 0; ni < 6; ++ni) bv[ni] = *(const bf16x8*)(pb + ni * 2048 + ch0);
#pragma unroll
    for (int mi = 0; mi < 4; ++mi) af[mi] = *(const bf16x8*)(pa + mi * 2048 + ch0);
#pragma unroll
    for (int mi = 0; mi < 4; ++mi)
#pragma unroll
      for (int ni = 0; ni < 6; ++ni)
        acc[mi][ni] = __builtin_amdgcn_mfma_f32_16x16x32_bf16(af[mi], bv[ni],
                                                              acc[mi][ni], 0, 0, 0);
    // k-half 1
#pragma unroll
    for (int ni = 0; ni < 6; ++ni) bv[ni] = *(const bf16x8*)(pb + ni * 2048 + ch1);
#pragma unroll
    for (int mi = 0; mi < 4; ++mi) af[mi] = *(const bf16x8*)(pa + mi * 2048 + ch1);
#pragma unroll
    for (int mi = 0; mi < 4; ++mi)
#pragma unroll
      for (int ni = 0; ni < 6; ++ni)
        acc[mi][ni] = __builtin_amdgcn_mfma_f32_16x16x32_bf16(af[mi], bv[ni],
                                                              acc[mi][ni], 0, 0, 0);

    if (kt + 1 < NT) {
      asm volatile("s_waitcnt lgkmcnt(0)" ::: "memory");  // my reads of buf[cb] done
      asm volatile("s_waitcnt vmcnt(0)" ::: "memory");    // my stages landed
      __builtin_amdgcn_s_barrier();                       // all waves ready
    }
  }

  const int rq = lane >> 4;
#pragma unroll
  for (int ni = 0; ni < 6; ++ni) {
    int n = nbase + wc * 96 + ni * 16 + fr;
    float bb = bias[n];
#pragma unroll
    for (int mi = 0; mi < 4; ++mi) {
      int mrow = mbase + wr * 64 + mi * 16 + rq * 4;
      f32x4 v = acc[mi][ni];
#pragma unroll
      for (int j = 0; j < 4; ++j) C[(size_t)(mrow + j) * N + n] = v[j] + bb;
    }
  }
}

extern "C" void kernel_launch(void* const* d_in, const int* in_sizes, int n_in,
                              void* d_out, int out_size, void* d_ws, size_t ws_size,
                              hipStream_t stream) {
  const float* x = (const float*)d_in[0];     // (128,3,224,224) f32
  const float* W = (const float*)d_in[1];     // (768,3,16,16)  f32
  const float* bias = (const float*)d_in[2];  // (768,)         f32
  float* out = (float*)d_out;                 // (128,196,768)  f32

  unsigned short* A = (unsigned short*)d_ws;                        // 25088*768 bf16
  unsigned short* Wb = (unsigned short*)((char*)d_ws + 38535168);   // 589824 bf16

  pre_kernel<<<5280, 256, 0, stream>>>(x, W, A, Wb);
  gemm_kernel<<<784, 256, 0, stream>>>(A, Wb, bias, out);
}